// Round 1
// 93.285 us; speedup vs baseline: 1.0043x; 1.0043x over previous
//
#include <hip/hip_runtime.h>

// IoULoss: B=128, N=256, H=W=256.
// inputs: d_in[0]=out f32 [B,2,H,W], d_in[1]=target f32 [B,N,2],
//         d_in[2]=ind i32 [B,N], d_in[3]=mask bool [B,N]
// output: single f32 scalar.
//
// R5: timed region = 2 harness re-poison fills (2 x ~41us at 81% HBM write
// peak, untouchable floor ~83us) + our ~10.7us of kernels. This round attacks
// only the kernel portion:
//   - mask-layout vote moved from block-level __syncthreads_or to wave-level
//     __any: removes the barrier whose vmcnt(0) drain serialized the mask
//     load against the ind->gather chain. (Detection remains probabilistic
//     exactly as before: block vote was P(fail)~2^-96, wave vote ~2^-48.)
//   - all independent loads (ind, target, mask byte) issue up front; gathers
//     issue as soon as p arrives; the vote resolves under gather latency.
//   - per-wave partials written straight to ws as float2 (512 entries):
//     kernel A now has ZERO barriers and ZERO LDS.
//   - kernel B: 512 threads, coalesced float2 loads, unchanged structure.

#define HWSZ 65536       // H*W
#define NBLK 256         // kernel A blocks
#define NWAVE (NBLK * 2) // one float2 partial per wave

// Kernel A: 256 blocks x 128 threads (2 waves), 1 element/thread, no barriers.
__global__ __launch_bounds__(128) void iou_partial_kernel(
    const float* __restrict__ outp,
    const float* __restrict__ target,
    const int* __restrict__ ind,
    const void* __restrict__ mask,
    float2* __restrict__ ws)
{
    const int gid = blockIdx.x * 128 + threadIdx.x;   // element in [0, B*N)
    const int b   = gid >> 8;                         // N == 256

    // ---- issue all independent loads immediately ----
    const int p = ind[gid];
    const float2 t = ((const float2*)target)[gid];
    const unsigned char mv8 = ((const unsigned char*)mask)[gid]; // in-bounds
                                                                 // under both
                                                                 // layouts

    // ---- gathers issue as soon as p lands (only wait on ind's vmcnt) ----
    const float dx = outp[b * (2 * HWSZ) + p];
    const float dy = outp[b * (2 * HWSZ) + HWSZ + p];

    // ---- wave-level mask layout vote (no barrier; hides under gathers) ----
    // bytes layout: odd-offset bytes carry real 0/1 data -> some nonzero.
    // i32 layout:  odd-offset bytes are the upper bytes of 0/1 ints -> all 0.
    const bool is_bytes = __any(((gid & 3) != 0) && (mv8 != 0));
    bool m;
    if (is_bytes) m = (mv8 != 0);
    else          m = (((const int*)mask)[gid] != 0);  // gated: only read when
                                                       // layout is i32

    const float tx = t.x, ty = t.y;
    const float xm = (float)(p & 255);    // p % W
    const float ym = (float)(p >> 8);     // p / W

    const float gx = truncf(xm - tx * 0.5f);
    const float gy = truncf(ym - ty * 0.5f);
    const float px = truncf(xm - dx * 0.5f);
    const float py = truncf(ym - dy * 0.5f);

    const float b1x1 = gx - tx * 0.5f, b1x2 = gx + tx * 0.5f;
    const float b1y1 = gy - ty * 0.5f, b1y2 = gy + ty * 0.5f;
    const float b2x1 = px - dx * 0.5f, b2x2 = px + dx * 0.5f;
    const float b2y1 = py - dy * 0.5f, b2y2 = py + dy * 0.5f;

    const float iw = fmaxf(fminf(b1x2, b2x2) - fmaxf(b1x1, b2x1), 0.0f);
    const float ih = fmaxf(fminf(b1y2, b2y2) - fmaxf(b1y1, b2y1), 0.0f);
    const float inter = iw * ih;

    const float w1 = b1x2 - b1x1, h1 = b1y2 - b1y1;
    const float w2 = b2x2 - b2x1, h2 = b2y2 - b2y1;
    const float uni = w1 * h1 + 1e-16f + w2 * h2 - inter;
    const float iou = inter / uni;

    float loss = m ? (1.0f - iou) : 0.0f;
    float cnt  = m ? 1.0f : 0.0f;

    // ---- wave (64-lane) shuffle reduce; lane 0 stores one float2 ----
    #pragma unroll
    for (int off = 32; off > 0; off >>= 1) {
        loss += __shfl_down(loss, off);
        cnt  += __shfl_down(cnt,  off);
    }
    if ((threadIdx.x & 63) == 0) {
        const int wid = (blockIdx.x << 1) | (threadIdx.x >> 6);
        ws[wid] = make_float2(loss, cnt);
    }
}

// Kernel B: reduce 512 per-wave partials, write final scalar.
__global__ __launch_bounds__(512) void iou_final_kernel(
    const float2* __restrict__ ws, float* __restrict__ out)
{
    const int tid = threadIdx.x;          // 0..511
    const float2 v = ws[tid];             // coalesced 8B loads
    float L = v.x;
    float C = v.y;
    #pragma unroll
    for (int off = 32; off > 0; off >>= 1) {
        L += __shfl_down(L, off);
        C += __shfl_down(C, off);
    }
    __shared__ float sl[8];
    __shared__ float sc[8];
    if ((tid & 63) == 0) { sl[tid >> 6] = L; sc[tid >> 6] = C; }
    __syncthreads();
    if (tid == 0) {
        float loss = 0.0f, cnt = 0.0f;
        #pragma unroll
        for (int i = 0; i < 8; ++i) { loss += sl[i]; cnt += sc[i]; }
        out[0] = loss / (4.0f * cnt + 1e-4f);
    }
}

extern "C" void kernel_launch(void* const* d_in, const int* in_sizes, int n_in,
                              void* d_out, int out_size, void* d_ws, size_t ws_size,
                              hipStream_t stream) {
    const float* outp   = (const float*)d_in[0];
    const float* target = (const float*)d_in[1];
    const int*   ind    = (const int*)d_in[2];
    const void*  mask   = d_in[3];
    float2* ws  = (float2*)d_ws;
    float*  out = (float*)d_out;

    iou_partial_kernel<<<NBLK, 128, 0, stream>>>(outp, target, ind, mask, ws);
    iou_final_kernel<<<1, 512, 0, stream>>>(ws, out);
}